// Round 6
// baseline (245.045 us; speedup 1.0000x reference)
//
#include <hip/hip_runtime.h>
#include <math.h>

#define BATCH 4096
#define SEQ_T 512
#define ISZ   4
#define HID   64
#define OSZ   40
#define RPB   16     // full MFMA N: 16 batch rows per block, 256 blocks = 1/CU
#define CHNK  32     // x timesteps staged per LDS chunk
#define NCH   (SEQ_T / CHNK)

typedef __attribute__((ext_vector_type(8))) _Float16     half8;
typedef __attribute__((ext_vector_type(2))) _Float16     half2v;
typedef __attribute__((ext_vector_type(4))) float        float4v;
typedef __attribute__((ext_vector_type(2))) unsigned int uint2v;

static __device__ __forceinline__ half2v pk_f16(float a, float b) {
    return __builtin_bit_cast(half2v, __builtin_amdgcn_cvt_pkrtz(a, b)); // v_cvt_pkrtz_f16_f32
}

// tanh(x) = 1 - 2/(exp(2x)+1); saturates to +/-1, NaN-free
static __device__ __forceinline__ float fast_tanh(float x) {
    float e = __expf(2.0f * x);
    return 1.0f - 2.0f * __builtin_amdgcn_rcpf(e + 1.0f);
}

__global__ __launch_bounds__(256, 1)
void rnn_f16x2s_kernel(const float* __restrict__ x,
                       const float* __restrict__ W_ih,
                       const float* __restrict__ W_hh,
                       const float* __restrict__ b_ih,
                       const float* __restrict__ b_hh,
                       const float* __restrict__ fc_W,
                       const float* __restrict__ fc_b,
                       float* __restrict__ out)
{
    // h terms, B-fragment-native: hterm[buf][tau][g][n][j] = h_tau[k=8g+j], batch col n.
    // Reader b128: banks (4n+d)%32 -> 2-way (free). Writer b64: 2-way.
    __shared__ __attribute__((aligned(16))) _Float16 hterm[2][2][8][16][8];
    // x chunk: [t][n][4] fp32, row stride 17*4 dwords -> banks (4t+4n+d)%32: 2-way.
    __shared__ __attribute__((aligned(16))) float xlds[CHNK][17][4];
    __shared__ __attribute__((aligned(16))) float hf[16][68];

    const int tid  = threadIdx.x;
    const int wv   = tid >> 6;
    const int lane = tid & 63;
    const int n    = lane & 15;    // A: row m; B/C/D: batch col n
    const int q    = lane >> 4;
    const int blk0 = blockIdx.x * RPB;

    // h(0) = 0: zero both buffers (visible after first chunk-boundary barrier)
    {
        unsigned int* p = (unsigned int*)hterm;
        #pragma unroll
        for (int i = tid; i < (int)(sizeof(hterm) / 4); i += 256) p[i] = 0u;
    }

    // ---- static A fragments: W_hh row 16wv+n, 2-term fp16 split, K-chunks c=0,1 ----
    half8 A10, A11, A20, A21;   // A1x = hi term, A2x = residual
    {
        const float* wr = W_hh + (16 * wv + n) * HID;
        #pragma unroll
        for (int j = 0; j < 8; ++j) {
            float f0 = wr[     8 * q + j];
            float f1 = wr[32 + 8 * q + j];
            _Float16 h0 = (_Float16)f0; A10[j] = h0; A20[j] = (_Float16)(f0 - (float)h0);
            _Float16 h1 = (_Float16)f1; A11[j] = h1; A21[j] = (_Float16)(f1 - (float)h1);
        }
    }

    // ---- fp32 x-projection weights + bias for C rows 16wv + 4q + r ----
    const int r0 = 16 * wv + 4 * q;
    float wih[4][4], bias[4];
    #pragma unroll
    for (int r = 0; r < 4; ++r) {
        bias[r] = b_ih[r0 + r] + b_hh[r0 + r];
        #pragma unroll
        for (int i = 0; i < ISZ; ++i) wih[r][i] = W_ih[(r0 + r) * ISZ + i];
    }

    // ---- x chunk staging: thread (sn, st) owns x[blk0+sn][c*32+st .. +st+1][:] ----
    const int sn = tid >> 4;          // batch row 0..15
    const int st = (tid & 15) * 2;    // timestep pair within chunk
    const float* xsrc = x + ((size_t)(blk0 + sn) * SEQ_T + st) * ISZ;
    float4v xr0 = *(const float4v*)(xsrc);        // chunk 0 prefetch
    float4v xr1 = *(const float4v*)(xsrc + 4);

    const int gw = 2 * wv + (q >> 1);
    const int j0 = 4 * (q & 1);

    float hl0 = 0.f, hl1 = 0.f, hl2 = 0.f, hl3 = 0.f;

#define MFMA16(A, B, C) __builtin_amdgcn_mfma_f32_16x16x32_f16((A), (B), (C), 0, 0, 0)
#define RNN_STEP(RB, WB, S)                                                    \
    {                                                                          \
        const float4v xv = *(const float4v*)&xlds[S][n][0];                    \
        half8 B10 = *(const half8*)&hterm[RB][0][    q][n][0];                 \
        half8 B11 = *(const half8*)&hterm[RB][0][4 + q][n][0];                 \
        half8 B20 = *(const half8*)&hterm[RB][1][    q][n][0];                 \
        half8 B21 = *(const half8*)&hterm[RB][1][4 + q][n][0];                 \
        float p0 = bias[0], p1 = bias[1], p2 = bias[2], p3 = bias[3];          \
        _Pragma("unroll")                                                      \
        for (int i = 0; i < ISZ; ++i) {                                        \
            p0 = fmaf(xv[i], wih[0][i], p0);                                   \
            p1 = fmaf(xv[i], wih[1][i], p1);                                   \
            p2 = fmaf(xv[i], wih[2][i], p2);                                   \
            p3 = fmaf(xv[i], wih[3][i], p3);                                   \
        }                                                                      \
        float4v accA = {p0, p1, p2, p3};                                       \
        float4v accB = {0.f, 0.f, 0.f, 0.f};                                   \
        accA = MFMA16(A10, B10, accA);  accB = MFMA16(A11, B11, accB);         \
        accA = MFMA16(A10, B20, accA);  accB = MFMA16(A11, B21, accB);         \
        accA = MFMA16(A20, B10, accA);  accB = MFMA16(A21, B11, accB);         \
        hl0 = fast_tanh(accA[0] + accB[0]); hl1 = fast_tanh(accA[1] + accB[1]);\
        hl2 = fast_tanh(accA[2] + accB[2]); hl3 = fast_tanh(accA[3] + accB[3]);\
        half2v hi01 = pk_f16(hl0, hl1), hi23 = pk_f16(hl2, hl3);               \
        float s0 = hl0 - (float)hi01[0], s1 = hl1 - (float)hi01[1];            \
        float s2 = hl2 - (float)hi23[0], s3 = hl3 - (float)hi23[1];            \
        half2v lo01 = pk_f16(s0, s1), lo23 = pk_f16(s2, s3);                   \
        uint2v whi = { __builtin_bit_cast(unsigned int, hi01),                 \
                       __builtin_bit_cast(unsigned int, hi23) };               \
        uint2v wlo = { __builtin_bit_cast(unsigned int, lo01),                 \
                       __builtin_bit_cast(unsigned int, lo23) };               \
        *(uint2v*)&hterm[WB][0][gw][n][j0] = whi;                              \
        *(uint2v*)&hterm[WB][1][gw][n][j0] = wlo;                              \
        __syncthreads();                                                       \
    }

    for (int c = 0; c < NCH; ++c) {
        // boundary: publish chunk c (from regs), prefetch chunk c+1
        *(float4v*)&xlds[st    ][sn][0] = xr0;
        *(float4v*)&xlds[st + 1][sn][0] = xr1;
        const int cn = (c + 1 < NCH) ? c + 1 : NCH - 1;
        const float* p = x + ((size_t)(blk0 + sn) * SEQ_T + cn * CHNK + st) * ISZ;
        xr0 = *(const float4v*)(p);
        xr1 = *(const float4v*)(p + 4);
        __syncthreads();   // xlds (+ hterm zero-init on c=0) visible; drains prefetch once/chunk

        #pragma unroll
        for (int s = 0; s < CHNK; s += 2) {
            RNN_STEP(0, 1, s)
            RNN_STEP(1, 0, s + 1)
        }
    }
#undef RNN_STEP
#undef MFMA16

    // ---- fc epilogue on fp32 final h (in registers) ----
    {
        float4v hv = {hl0, hl1, hl2, hl3};
        *(float4v*)&hf[n][16 * wv + 4 * q] = hv;
    }
    __syncthreads();
    for (int it = tid; it < RPB * OSZ; it += 256) {
        const int b = it / OSZ;
        const int o = it - b * OSZ;
        const float* wo = fc_W + o * HID;
        float acc = fc_b[o];
        #pragma unroll
        for (int j = 0; j < HID; ++j)
            acc = fmaf(hf[b][j], wo[j], acc);
        out[(size_t)(blk0 + b) * OSZ + o] = acc;
    }
}

extern "C" void kernel_launch(void* const* d_in, const int* in_sizes, int n_in,
                              void* d_out, int out_size, void* d_ws, size_t ws_size,
                              hipStream_t stream) {
    const float* x    = (const float*)d_in[0];
    const float* W_ih = (const float*)d_in[1];
    const float* W_hh = (const float*)d_in[2];
    const float* b_ih = (const float*)d_in[3];
    const float* b_hh = (const float*)d_in[4];
    const float* fc_W = (const float*)d_in[5];
    const float* fc_b = (const float*)d_in[6];
    float* out = (float*)d_out;

    rnn_f16x2s_kernel<<<BATCH / RPB, 256, 0, stream>>>(
        x, W_ih, W_hh, b_ih, b_hh, fc_W, fc_b, out);
}